// Round 8
// baseline (4990.604 us; speedup 1.0000x reference)
//
#include <hip/hip_runtime.h>
#include <stdint.h>

// FPS: B=16, C=3, N=131072, M=2048. 128 blocks (8/batch) x 1024 thr.
//
// R14 = R12 protocol with HALF the consensus participants:
//       8 blocks/batch x 16 points/thread (was 16 blocks x 8 pts).
//  - R13 post-mortem: 256thr/32pt reshape = 0.4% delta vs R6/R12 =>
//    compute issue, barrier width, reduce width all OFF the critical path.
//    Round floor 2.04 us is set by the cross-block consensus itself. The
//    one never-varied parameter: participant count (16). Both remaining
//    candidate costs scale with it: hot-line serialization at the fabric
//    ordering point (16 stores + 16 poll streams/round) and max-over-16
//    detection-latency straggler jitter. R14 isolates participant count:
//    8 publishes + 8 poll targets (64 B line), max-over-8 jitter, same
//    per-SIMD compute issue as R6 (4 waves x 16 STEPs ~ proven hidden).
//  - Everything else R12-verbatim (absmax 0 verified R12/R13): tagged u64
//    slot/block, wave0-only depth-2 pipelined agent poll (counted vmcnt,
//    rule-18 fences), coord prefetch under final butterfly, winC relay.
// Numerics (bit-matches XLA-CPU ref): d = fma(dz,dz, fma(dy,dy, dx*dx));
// ascending candidate order + strict '>' keeps first max in-thread; packed
// key [distBits:32][invIdx:17] ties toward smallest global index; winner
// coords re-read from px[] => bit-identical output.

#define NBATCH    16
#define NPTS      131072
#define SUBBLOCKS 8
#define NTHREADS  1024
#define NWAVES    (NTHREADS / 64)
#define CHUNK     16384         // points per block
#define GOFF      4096          // stride between the 4 groups

typedef unsigned long long u64;

__device__ __forceinline__ u64 umax64(u64 a, u64 b) { return a > b ? a : b; }

__global__ __launch_bounds__(NTHREADS, 1)
void fps_kernel(const float* __restrict__ points,
                float* __restrict__ out,
                u64* __restrict__ slots, int M)
{
  __shared__ u64 wkeys[NWAVES];
  __shared__ float winC[3];

  const int bid   = blockIdx.x;
  const int xcd   = bid & 7;                 // XCD swizzle: batch co-XCD
  const int ord   = bid >> 3;                // 0..15
  const int batch = xcd * 2 + (ord >> 3);
  const int sub   = ord & 7;
  const int tid   = threadIdx.x;
  const int wave  = tid >> 6;
  const int lane  = tid & 63;

  const float* __restrict__ px = points + (size_t)batch * 3 * NPTS;
  const float* __restrict__ py = px + NPTS;
  const float* __restrict__ pz = px + 2 * NPTS;
  float* outb = out + (size_t)batch * 3 * M;
  u64* bslots = slots + (size_t)batch * 2 * SUBBLOCKS;

  const int cbase = sub * CHUNK;
  const int gbase = cbase + (tid << 2);      // candidate 0 of this thread

  // 16 points/thread: 4 groups of 4, group g at gbase + g*4096.
  // Coalesced: 1024 threads x 16 B = 16 KB contiguous per (plane, group).
  float4 X[4], Y[4], Z[4], D[4];
#pragma unroll
  for (int g = 0; g < 4; ++g) {
    X[g] = *(const float4*)(px + gbase + g * GOFF);
    Y[g] = *(const float4*)(py + gbase + g * GOFF);
    Z[g] = *(const float4*)(pz + gbase + g * GOFF);
  }
  // Pin all 48 coord floats in VGPRs (R2/R3: compiler otherwise sinks the
  // loads back into the loop).
#define PIN(G) asm volatile("" : \
    "+v"(X[G].x),"+v"(X[G].y),"+v"(X[G].z),"+v"(X[G].w), \
    "+v"(Y[G].x),"+v"(Y[G].y),"+v"(Y[G].z),"+v"(Y[G].w), \
    "+v"(Z[G].x),"+v"(Z[G].y),"+v"(Z[G].z),"+v"(Z[G].w));
  PIN(0) PIN(1) PIN(2) PIN(3)

#pragma unroll
  for (int g = 0; g < 4; ++g)
    D[g].x = D[g].y = D[g].z = D[g].w = __builtin_inff();

  // Selection 0 is index 0 by convention.
  if (sub == 0 && tid == 0) {
    outb[0]     = px[0];
    outb[M]     = py[0];
    outb[2 * M] = pz[0];
  }
  float cx = px[0], cy = py[0], cz = pz[0];

  for (int t = 1; t < M; ++t) {
    float best = -1.0f;
    int bj = 0;   // 4-bit candidate id g*4+j (inline-const cndmask source)
    // d = fma(dz,dz, fma(dy,dy, dx*dx)) : bit-matches the reference chain.
    // Ascending candidate order (g outer, j inner = ascending global idx)
    // + strict '>' keeps the first (smallest-index) max within the thread.
#define STEP1(G, C, J) { \
    float dx = __fsub_rn(X[G].C, cx); \
    float dy = __fsub_rn(Y[G].C, cy); \
    float dz = __fsub_rn(Z[G].C, cz); \
    float dd = __builtin_fmaf(dz, dz, __builtin_fmaf(dy, dy, __fmul_rn(dx, dx))); \
    float dn = D[G].C < dd ? D[G].C : dd; \
    D[G].C = dn; \
    if (dn > best) { best = dn; bj = 4 * (G) + (J); } }
#define STEPG(G) STEP1(G, x, 0) STEP1(G, y, 1) STEP1(G, z, 2) STEP1(G, w, 3)
    STEPG(0) STEPG(1) STEPG(2) STEPG(3)

    // Reconstruct global index once: gbase + (bj>>2)*4096 + (bj&3).
    const int bidx = gbase + ((bj >> 2) << 12) + (bj & 3);
    // Pack [distBits:32 @17][invIdx:17 @0]; non-negative f32 bits are
    // order-preserving; invIdx breaks ties toward the SMALLEST index.
    u64 key = ((u64)__float_as_uint(best) << 17) | (u64)((NPTS - 1) - bidx);

    // Per-wave butterfly (parallel across all 16 waves).
#pragma unroll
    for (int m = 32; m >= 1; m >>= 1) {
      u64 o = __shfl_xor(key, m, 64);
      key = umax64(key, o);
    }
    if (lane == 0) wkeys[wave] = key;
    __syncthreads();

    if (wave == 0) {
      // Block reduce over 16 wave winners: mirror wkeys[lane&15]
      // (same-address broadcasts free), 4-step butterfly.
      u64 k = wkeys[lane & 15];
#pragma unroll
      for (int m = 8; m >= 1; m >>= 1) {
        u64 o = __shfl_xor(k, m, 64);
        k = umax64(k, o);
      }
      // Publish tagged block winner: ONE u64/block, 8 slots = one 64 B
      // line per batch — HALF the hot-line traffic of R6/R12.
      u64* par = bslots + (size_t)(t & 1) * SUBBLOCKS;
      if (lane == 0) {
        __hip_atomic_store(par + sub, ((u64)t << 49) | k,
                           __ATOMIC_RELAXED, __HIP_MEMORY_SCOPE_AGENT);
      }
      const u64* pp = par + (lane & 7);

      // Zero the vmcnt baseline (drains publish + pending outb stores) so
      // the counted vmcnt(1) below refers exactly to our poll loads.
      asm volatile("s_waitcnt vmcnt(0)" ::: "memory");

      // Pipelined poll, depth 2 (R12-proven): two agent loads in flight;
      // counted s_waitcnt vmcnt(1); tag-validated => stale samples fail.
      u64 va, vb, v;
      asm volatile("global_load_dwordx2 %0, %1, off sc0 sc1"
                   : "=v"(va) : "v"(pp) : "memory");
      asm volatile("global_load_dwordx2 %0, %1, off sc0 sc1"
                   : "=v"(vb) : "v"(pp) : "memory");
      for (;;) {
        asm volatile("s_waitcnt vmcnt(1)" ::: "memory");   // va landed
        __builtin_amdgcn_sched_barrier(0);                 // rule-18 fence
        if (__ballot((unsigned)(va >> 49) == (unsigned)t) == ~0ull) { v = va; break; }
        asm volatile("global_load_dwordx2 %0, %1, off sc0 sc1"
                     : "=v"(va) : "v"(pp) : "memory");
        asm volatile("s_waitcnt vmcnt(1)" ::: "memory");   // vb landed
        __builtin_amdgcn_sched_barrier(0);
        if (__ballot((unsigned)(vb >> 49) == (unsigned)t) == ~0ull) { v = vb; break; }
        asm volatile("global_load_dwordx2 %0, %1, off sc0 sc1"
                     : "=v"(vb) : "v"(pp) : "memory");
      }

      // Coord prefetch under the final butterfly (R12): lane<8 issues its
      // candidate's coords; unique winner lane (keys unique by invIdx)
      // drops 3 floats into LDS. Coords read from px[] => bit-exact.
      int cidx = (NPTS - 1) - (int)(v & 0x1FFFF);
      float qx = 0.f, qy = 0.f, qz = 0.f;
      if (lane < 8) { qx = px[cidx]; qy = py[cidx]; qz = pz[cidx]; }
      u64 kk = v;
#pragma unroll
      for (int m = 4; m >= 1; m >>= 1) {
        u64 o = __shfl_xor(kk, m, 64);
        kk = umax64(kk, o);
      }
      if (lane < 8 && v == kk) { winC[0] = qx; winC[1] = qy; winC[2] = qz; }
      // Drain the orphan in-flight poll load while va/vb are still live so
      // a landing load can never corrupt a reallocated register.
      asm volatile("s_waitcnt vmcnt(0)" :: "v"(va), "v"(vb) : "memory");
    }
    __syncthreads();

    cx = winC[0]; cy = winC[1]; cz = winC[2];
    if (sub == 0 && tid == 0) {
      outb[t]         = cx;
      outb[M + t]     = cy;
      outb[2 * M + t] = cz;
    }
  }
}

extern "C" void kernel_launch(void* const* d_in, const int* in_sizes, int n_in,
                              void* d_out, int out_size, void* d_ws, size_t ws_size,
                              hipStream_t stream) {
  (void)in_sizes; (void)n_in; (void)ws_size;
  const float* points = (const float*)d_in[0];
  float* out = (float*)d_out;
  u64* slots = (u64*)d_ws;
  const int M = out_size / (NBATCH * 3);   // 2048

  // Zero barrier slots (stale tags must not alias t in 1..M-1).
  hipMemsetAsync(d_ws, 0, (size_t)NBATCH * 2 * SUBBLOCKS * sizeof(u64), stream);

  hipLaunchKernelGGL(fps_kernel, dim3(NBATCH * SUBBLOCKS), dim3(NTHREADS), 0,
                     stream, points, out, slots, M);
}